// Round 6
// baseline (423.674 us; speedup 1.0000x reference)
//
#include <hip/hip_runtime.h>

// Problem constants
#define DD 128    // nodes / input dim
#define HH 512    // hidden
#define NN 2048   // batch rows
#define NT 64     // rows per block tile
#define PLD 516   // pack LDS leading dim

typedef __bf16 bf16x8 __attribute__((ext_vector_type(8)));
typedef __bf16 bf16x4 __attribute__((ext_vector_type(4)));
typedef float  floatx4 __attribute__((ext_vector_type(4)));
typedef float  floatx16 __attribute__((ext_vector_type(16)));

// ---------------------------------------------------------------------------
// x (fp32 row-major) -> xb (bf16 row-major). 2048x128, 16B/thread.
// ---------------------------------------------------------------------------
__global__ void cvt_x(const float* __restrict__ x, __bf16* __restrict__ xb) {
    int t = blockIdx.x * blockDim.x + threadIdx.x;
    float4 v = *(const float4*)(x + (size_t)t * 4);
    bf16x4 o;
    o[0] = (__bf16)v.x; o[1] = (__bf16)v.y; o[2] = (__bf16)v.z; o[3] = (__bf16)v.w;
    *(bf16x4*)(xb + (size_t)t * 4) = o;
}

// ---------------------------------------------------------------------------
// Pack W[d][K][H] fp32 -> bf16 32x32x16-MFMA fragment order via LDS transpose.
//   frag(d, ct, ks): lane l (m=l&31, q=l>>5) holds W[16ks+8q+j][32ct+m], j=0..7
//   Wp[(((d*16+ct)*nks16 + ks)*64 + l)*8 + j]
// Serves as A-frag of W^T (A[m][k]=W[k][m]) for the transposed-operand MFMA.
// One block per (d, 32 k-rows): coalesced float4 reads, LDS transpose,
// coalesced 16B writes (1KB per wave-instr).
// ---------------------------------------------------------------------------
__global__ void pack_w(const float* __restrict__ W, __bf16* __restrict__ Wp, int nks32) {
    __shared__ __bf16 Ls[32 * PLD];
    const int d  = blockIdx.x / nks32;
    const int kb = blockIdx.x % nks32;
    const int tid = threadIdx.x;
    const int nks16 = nks32 * 2;
    const float* src = W + ((size_t)(d * nks32 + kb) * 32) * HH;

#pragma unroll
    for (int it = 0; it < 16; ++it) {
        int e = (it * 256 + tid) * 4;   // row=e>>9 (k), col=e&511
        float4 v = *(const float4*)(src + e);
        bf16x4 o;
        o[0] = (__bf16)v.x; o[1] = (__bf16)v.y; o[2] = (__bf16)v.z; o[3] = (__bf16)v.w;
        *(bf16x4*)(Ls + (e >> 9) * PLD + (e & 511)) = o;
    }
    __syncthreads();

#pragma unroll
    for (int it = 0; it < 8; ++it) {
        int idx = it * 256 + tid;       // 0..2047
        int l   = idx & 63;
        int m   = l & 31;
        int q   = l >> 5;
        int h   = (idx >> 6) & 1;       // ks half within the 32-row slab
        int ct  = idx >> 7;             // 0..15
        bf16x8 v;
#pragma unroll
        for (int j = 0; j < 8; ++j)
            v[j] = Ls[(h * 16 + q * 8 + j) * PLD + ct * 32 + m];
        *(bf16x8*)(Wp + (((size_t)(d * 16 + ct) * nks16 + (2 * kb + h)) * 64 + l) * 8) = v;
    }
}

// ---------------------------------------------------------------------------
// Fused per-(d, row-tile) MLP, transposed operand order, 32x32x16 MFMA
// (2495 TF measured vs 2075 for 16x16x32; 2x FLOP per operand byte).
//   mfma(Wfrag, Xfrag) => D = (X.W)^T: lane lc5 holds output ROW 32nt+lc5,
//   cols (reg&3)+8*(reg>>2)+4*q2 within the mt tile -> b64 h1 stores.
// h1s: 64x512 bf16, 16B chunks XOR-swizzled by row&7 (balanced 8 lanes per
// bank-group, the b128 minimum).
// VGPR discipline ((512,4) cap = 64V+64A): wf[2] resident, xf/hf one at a
// time, uniform bases hoisted to SGPRs.
// ---------------------------------------------------------------------------
__launch_bounds__(512, 4)
__global__ void grandag_main(const __bf16* __restrict__ xb,
                             const __bf16* __restrict__ W0p,
                             const __bf16* __restrict__ W1p,
                             const float* __restrict__ W2,
                             float* __restrict__ out) {
    __shared__ __bf16 h1s[NT * HH];   // 65536 B
    __shared__ float  outp[NT];       // -> 2 blocks/CU

    const int b  = blockIdx.x;
    // XCD swizzle: d % 8 == blockIdx % 8 -> all 32 tiles of a d on one XCD
    const int d  = ((b >> 8) << 3) | (b & 7);
    const int n0 = ((b >> 3) & 31) * NT;

    const int tid = threadIdx.x;
    const int w   = tid >> 6;   // wave 0..7: owns h-cols [w*64, w*64+64)
    const int l   = tid & 63;
    const int lc5 = l & 31;     // 32x32 C/D col = batch row (transposed form)
    const int q2  = l >> 5;     // k-half / col sub-offset
    const int lane8 = l * 8;    // frag offset in elements

    const int ksz = d >> 4;          // 16-wide k-step containing column d of X
    const int qz  = (d >> 3) & 1;    // half containing it
    const int jz  = d & 7;           // element containing it

    if (tid < NT) outp[tid] = 0.f;

    // ---- phase 1: acc[mt][nt] = W0[d]^T (cols 64w+32mt..) . Xmask^T (rows 32nt..)
    {
        floatx16 acc[2][2] = {};
        const __bf16* W0b = W0p + ((size_t)(d * 16 + 2 * w) * 8) * 512 + lane8;
        const __bf16* xbb = xb + (size_t)(n0 + lc5) * DD + q2 * 8;
#pragma unroll
        for (int ks = 0; ks < 8; ks++) {
            bf16x8 wf[2];
#pragma unroll
            for (int mt = 0; mt < 2; mt++)
                wf[mt] = *(const bf16x8*)(W0b + (size_t)(mt * 8 + ks) * 512);
            const bool domask = (ks == ksz) && (q2 == qz);
#pragma unroll
            for (int nt = 0; nt < 2; nt++) {
                bf16x8 xf = *(const bf16x8*)(xbb + (size_t)(32 * nt) * DD + ks * 16);
                if (domask) {
#pragma unroll
                    for (int j = 0; j < 8; j++)
                        if (j == jz) xf[j] = (__bf16)0.f;
                }
#pragma unroll
                for (int mt = 0; mt < 2; mt++)
                    acc[mt][nt] = __builtin_amdgcn_mfma_f32_32x32x16_bf16(
                        wf[mt], xf, acc[mt][nt], 0, 0, 0);
            }
        }
        // epilogue: lane holds h1[row=32nt+lc5][col=64w+32mt+8g2+4q2+e], e=0..3
#pragma unroll
        for (int mt = 0; mt < 2; mt++)
#pragma unroll
            for (int nt = 0; nt < 2; nt++) {
                const int row = 32 * nt + lc5;
#pragma unroll
                for (int g2 = 0; g2 < 4; g2++) {
                    bf16x4 o;
#pragma unroll
                    for (int e = 0; e < 4; e++) {
                        float v = acc[mt][nt][g2 * 4 + e];
                        o[e] = (__bf16)fmaxf(v, 0.01f * v);   // leaky relu
                    }
                    const int cw = w * 8 + mt * 4 + g2;       // logical 16B chunk
                    *(bf16x4*)(h1s + row * HH + ((cw ^ (row & 7)) << 3) + (q2 << 2)) = o;
                }
            }
    }
    __syncthreads();

    // ---- phase 2: acc2[mt][nt] = W1[d]^T (cols 64w+32mt..) . h1^T (rows 32nt..)
    floatx16 acc2[2][2] = {};
    {
        const __bf16* W1b = W1p + ((size_t)(d * 16 + 2 * w) * 32) * 512 + lane8;
        const __bf16* h1b = h1s + lc5 * HH;
#pragma unroll
        for (int ks = 0; ks < 32; ks++) {
            bf16x8 wf[2];
#pragma unroll
            for (int mt = 0; mt < 2; mt++)
                wf[mt] = *(const bf16x8*)(W1b + (size_t)(mt * 32 + ks) * 512);
#pragma unroll
            for (int nt = 0; nt < 2; nt++) {
                const int row = 32 * nt + lc5;
                bf16x8 hf = *(const bf16x8*)(h1s + row * HH +
                                             (((2 * ks + q2) ^ (row & 7)) << 3));
#pragma unroll
                for (int mt = 0; mt < 2; mt++)
                    acc2[mt][nt] = __builtin_amdgcn_mfma_f32_32x32x16_bf16(
                        wf[mt], hf, acc2[mt][nt], 0, 0, 0);
            }
        }
        (void)h1b;
    }

    // ---- phase 3: out = leaky(h2) @ W2[d]; lane lc5 holds rows 32nt+lc5
    {
        const float* W2b = W2 + (size_t)d * HH + w * 64 + 4 * q2;
#pragma unroll
        for (int nt = 0; nt < 2; nt++) {
            float s = 0.f;
#pragma unroll
            for (int mt = 0; mt < 2; mt++)
#pragma unroll
                for (int g2 = 0; g2 < 4; g2++) {
                    floatx4 w2q = *(const floatx4*)(W2b + mt * 32 + 8 * g2);
#pragma unroll
                    for (int e = 0; e < 4; e++) {
                        float v = acc2[mt][nt][g2 * 4 + e];
                        s += fmaxf(v, 0.01f * v) * w2q[e];
                    }
                }
            // q2 pair holds the same row: fold, then cross-wave via LDS atomics
            s += __shfl_xor(s, 32, 64);
            if (l < 32) atomicAdd(&outp[32 * nt + lc5], s);
        }
    }
    __syncthreads();
    if (tid < NT) out[(size_t)(n0 + tid) * DD + d] = outp[tid];
}

// ---------------------------------------------------------------------------
extern "C" void kernel_launch(void* const* d_in, const int* in_sizes, int n_in,
                              void* d_out, int out_size, void* d_ws, size_t ws_size,
                              hipStream_t stream) {
    const float* x  = (const float*)d_in[0];
    const float* W0 = (const float*)d_in[1];
    const float* W1 = (const float*)d_in[2];
    const float* W2 = (const float*)d_in[3];
    float* out = (float*)d_out;

    __bf16* W0p = (__bf16*)d_ws;                                          // 16.8 MB
    __bf16* W1p = (__bf16*)((char*)d_ws + (size_t)DD * DD * HH * 2);      // 67.1 MB
    __bf16* xb  = (__bf16*)((char*)d_ws + (size_t)DD * DD * HH * 2
                                        + (size_t)DD * HH * HH * 2);      // 0.5 MB

    cvt_x<<<dim3(NN * DD / (256 * 4)), 256, 0, stream>>>(x, xb);
    pack_w<<<dim3(DD * (DD / 32)), 256, 0, stream>>>(W0, W0p, DD / 32);   // 512 blocks
    pack_w<<<dim3(DD * (HH / 32)), 256, 0, stream>>>(W1, W1p, HH / 32);   // 2048 blocks

    grandag_main<<<dim3(DD * (NN / NT)), 512, 0, stream>>>(xb, W0p, W1p, W2, out);
}